// Round 4
// baseline (1331.058 us; speedup 1.0000x reference)
//
#include <hip/hip_runtime.h>

typedef unsigned short u16;
typedef unsigned int u32;

#define N_NODES 50000
#define NB      64

// ws regions (u16 element offsets). Total 393216 u16 = 786432 bytes.
#define BG_OFF  0         // g-part B: N=4096 cols, K=64  -> 256 ntiles * 1024
#define BT_OFF  262144    // t-part B: N=1024 cols, K=64  ->  64 ntiles * 1024
#define BH_OFF  327680    // h-part B: N=2048 cols, K=32  -> 128 ntiles * 512

// LDS strides
#define ASTR   72   // A_S row stride (u16): 144B = 9 x 16B (odd -> conflict-free b128)
#define AHSTR  40   // A_H row stride (u16): 80B  = 5 x 16B
#define XTSTR  68   // x0T/x1T row stride (f32): 272B, 16B-aligned rows

typedef __attribute__((ext_vector_type(8))) short short8;
typedef __attribute__((ext_vector_type(4))) float f32x4;
union U4S8 { uint4 u; short8 s; };

__device__ __forceinline__ u16 f2bf(float f) {   // RNE f32 -> bf16
    u32 u = __float_as_uint(f);
    return (u16)((u + 0x7fffu + ((u >> 16) & 1u)) >> 16);
}

// ---------------- pack: weights -> bf16, MFMA-B-fragment-ordered ----------------
// B-frag for 16x16x32: lane = quad*16 + l15 holds B[col = ntile*16 + l15][k = ks*32 + quad*8 + jj].
// Storage slot within ntile: ks*512 + lane*8 + jj.
__global__ __launch_bounds__(256)
void pack_kernel(const float* __restrict__ W1, const float* __restrict__ W2,
                 const float* __restrict__ W3, const float* __restrict__ W4,
                 const float* __restrict__ W5, u16* __restrict__ ws) {
    const float INV_SQRT3 = 0.57735026918962576f;
    int T = blockIdx.x * 256 + threadIdx.x;
    float val;
    if (T < BT_OFF) {                       // g-part: Ŵ0[v, u, w], j = u*64+w
        int slot = T;
        int ntile = slot >> 10, rem = slot & 1023;
        int ks = rem >> 9, rem2 = rem & 511;
        int lane = rem2 >> 3, jj = rem2 & 7;
        int v = ks * 32 + (lane >> 4) * 8 + jj;
        int j = ntile * 16 + (lane & 15);
        int u = j >> 6, w = j & 63;
        if (v == u) val = W2[v * 64 + w];
        else {
            int a = min(u, v), b = max(u, v);
            int p = a * (127 - a) / 2 + (b - a - 1);   // triu64 k=1 row-major
            val = 0.5f * W1[p * 64 + w];
        }
    } else if (T < BH_OFF) {                // t-part: W3[u, v, w], j = u*32+w
        int slot = T - BT_OFF;
        int ntile = slot >> 10, rem = slot & 1023;
        int ks = rem >> 9, rem2 = rem & 511;
        int lane = rem2 >> 3, jj = rem2 & 7;
        int v = ks * 32 + (lane >> 4) * 8 + jj;
        int j = ntile * 16 + (lane & 15);
        int u = j >> 5, w = j & 31;
        val = W3[(u * 64 + v) * 32 + w];
    } else {                                // h-part: Ŵ1[v, u, w], j = u*64+w, K=32
        int slot = T - BH_OFF;
        int ntile = slot >> 9, rem = slot & 511;
        int lane = rem >> 3, jj = rem & 7;
        int v = (lane >> 4) * 8 + jj;
        int j = ntile * 16 + (lane & 15);
        int u = j >> 6, w = j & 63;
        if (v == u) val = W5[v * 64 + w] * INV_SQRT3;
        else {
            int a = min(u, v), b = max(u, v);
            int p = a * (63 - a) / 2 + (b - a - 1);    // triu32 k=1
            val = W4[p * 64 + w] * (0.5f * INV_SQRT3);
        }
    }
    ws[T] = f2bf(val);
}

// ---------------- main fused kernel: one barrier, register-resident A ----------------
__global__ __launch_bounds__(256, 2)
void node_block_kernel(const float* __restrict__ feats, const float* __restrict__ msgs,
                       const u16* __restrict__ ws, float* __restrict__ out) {
    __shared__ u16  A_S[64 * ASTR];      //  9216 B  bf16 x0 tile   (rows n, cols v<64)
    __shared__ u16  A_H[192 * AHSTR];    // 15360 B  bf16 x1 tile   (rows i*64+n, cols u<32)
    __shared__ float x0T[64 * XTSTR];    // 17408 B  f32  x0^T      ([v][n])
    __shared__ float x1T[96 * XTSTR];    // 26112 B  f32  x1^T      ([u*3+i][n])
    // total 68096 B -> 2 blocks/CU

    const int tid = threadIdx.x;
    const int node0 = blockIdx.x * NB;

    // ---- staging: x = feats + msgs, scattered into all 4 LDS forms ----
    for (int k = 0; k < 5; ++k) {
        int chunk = tid + k * 256;
        int idx = chunk * 8;                 // 160 % 8 == 0: never straddles nodes
        int n = (u32)idx / 160u;
        int d = idx - n * 160;
        int g = node0 * 160 + idx;
        float v[8];
        if (g + 8 <= N_NODES * 160) {
            float4 fa0 = *(const float4*)(feats + g);
            float4 fa1 = *(const float4*)(feats + g + 4);
            float4 fb0 = *(const float4*)(msgs + g);
            float4 fb1 = *(const float4*)(msgs + g + 4);
            v[0]=fa0.x+fb0.x; v[1]=fa0.y+fb0.y; v[2]=fa0.z+fb0.z; v[3]=fa0.w+fb0.w;
            v[4]=fa1.x+fb1.x; v[5]=fa1.y+fb1.y; v[6]=fa1.z+fb1.z; v[7]=fa1.w+fb1.w;
        } else {
            #pragma unroll
            for (int j = 0; j < 8; ++j) v[j] = 0.f;
        }
        if (d < 64) {                        // x0 chunk (d..d+7 all < 64)
            uint4 pk;
            pk.x = ((u32)f2bf(v[1]) << 16) | f2bf(v[0]);
            pk.y = ((u32)f2bf(v[3]) << 16) | f2bf(v[2]);
            pk.z = ((u32)f2bf(v[5]) << 16) | f2bf(v[4]);
            pk.w = ((u32)f2bf(v[7]) << 16) | f2bf(v[6]);
            *(uint4*)&A_S[n * ASTR + d] = pk;
            #pragma unroll
            for (int j = 0; j < 8; ++j) x0T[(d + j) * XTSTR + n] = v[j];
        } else {                             // x1 chunk (d..d+7 all >= 64)
            #pragma unroll
            for (int j = 0; j < 8; ++j) {
                int dd = d + j - 64;
                int u = (u32)dd / 3u, i = dd - u * 3;
                A_H[(i * 64 + n) * AHSTR + u] = f2bf(v[j]);
                x1T[(u * 3 + i) * XTSTR + n] = v[j];
            }
        }
    }
    __syncthreads();     // the ONLY barrier

    const int wave = tid >> 6, lane = tid & 63, quad = lane >> 4, l15 = lane & 15;

    // A_S fragments, register-resident: A[row = mt*16+l15][k = ks*32 + quad*8 + jj]
    short8 aS[4][2];
    #pragma unroll
    for (int mt = 0; mt < 4; ++mt)
        #pragma unroll
        for (int ks = 0; ks < 2; ++ks) {
            U4S8 t; t.u = *(const uint4*)&A_S[(mt * 16 + l15) * ASTR + ks * 32 + quad * 8];
            aS[mt][ks] = t.s;
        }

    const f32x4 z4 = {0.f, 0.f, 0.f, 0.f};
    f32x4 o0[4];                       // out0 accumulators: [mt] over rr; w-col = wq*16+l15
    #pragma unroll
    for (int mt = 0; mt < 4; ++mt) o0[mt] = z4;

    // ================ stage S: g = x0 @ Ŵ0, contract with x0 in-register ================
    const int wq = wave;                         // wave owns w-range [wq*16, wq*16+16)
    {
        const u16* bp = ws + BG_OFF + (u32)wq * 1024 + lane * 8;   // + u*4096 per u
        U4S8 b0c, b1c, b0n, b1n;
        b0c.u = *(const uint4*)(bp);
        b1c.u = *(const uint4*)(bp + 512);
        for (int u = 0; u < 64; ++u) {
            if (u < 63) {
                b0n.u = *(const uint4*)(bp + 4096);
                b1n.u = *(const uint4*)(bp + 4096 + 512);
            } else { b0n = b0c; b1n = b1c; }
            bp += 4096;
            f32x4 acc[4];
            #pragma unroll
            for (int mt = 0; mt < 4; ++mt) acc[mt] = z4;
            #pragma unroll
            for (int mt = 0; mt < 4; ++mt)
                acc[mt] = __builtin_amdgcn_mfma_f32_16x16x32_bf16(aS[mt][0], b0c.s, acc[mt], 0, 0, 0);
            #pragma unroll
            for (int mt = 0; mt < 4; ++mt)
                acc[mt] = __builtin_amdgcn_mfma_f32_16x16x32_bf16(aS[mt][1], b1c.s, acc[mt], 0, 0, 0);
            // out0[n, w] += x0[n, u] * g[n, u, w]   (broadcast reads: 4 addrs/instr)
            #pragma unroll
            for (int mt = 0; mt < 4; ++mt) {
                f32x4 xq = *(const f32x4*)&x0T[u * XTSTR + mt * 16 + quad * 4];
                o0[mt] += xq * acc[mt];
            }
            b0c = b0n; b1c = b1n;
        }
    }

    // ================ stage T: t = x0 @ W3', contract with x1 -> out1 ================
    {
        const int mh = wave >> 1, wh = wave & 1;     // wave owns (rows mh*32.., w-range wh*16..)
        f32x4 o1[3][2];                              // [i][mtl] over rr
        #pragma unroll
        for (int i = 0; i < 3; ++i)
            #pragma unroll
            for (int m = 0; m < 2; ++m) o1[i][m] = z4;

        const u16* bp = ws + BT_OFF + (u32)wh * 1024 + lane * 8;   // + u*2048 per u
        U4S8 b0c, b1c, b0n, b1n;
        b0c.u = *(const uint4*)(bp);
        b1c.u = *(const uint4*)(bp + 512);
        for (int u = 0; u < 32; ++u) {
            if (u < 31) {
                b0n.u = *(const uint4*)(bp + 2048);
                b1n.u = *(const uint4*)(bp + 2048 + 512);
            } else { b0n = b0c; b1n = b1c; }
            bp += 2048;
            f32x4 acc[2];
            #pragma unroll
            for (int m = 0; m < 2; ++m) acc[m] = z4;
            #pragma unroll
            for (int m = 0; m < 2; ++m)
                acc[m] = __builtin_amdgcn_mfma_f32_16x16x32_bf16(aS[mh * 2 + m][0], b0c.s, acc[m], 0, 0, 0);
            #pragma unroll
            for (int m = 0; m < 2; ++m)
                acc[m] = __builtin_amdgcn_mfma_f32_16x16x32_bf16(aS[mh * 2 + m][1], b1c.s, acc[m], 0, 0, 0);
            #pragma unroll
            for (int i = 0; i < 3; ++i)
                #pragma unroll
                for (int m = 0; m < 2; ++m) {
                    f32x4 xq = *(const f32x4*)&x1T[(u * 3 + i) * XTSTR + (mh * 2 + m) * 16 + quad * 4];
                    o1[i][m] += xq * acc[m];
                }
            b0c = b0n; b1c = b1n;
        }
        const float S1 = 0.022097087f;               // C1/sqrt(3) = sqrt(1/2048)
        #pragma unroll
        for (int i = 0; i < 3; ++i)
            #pragma unroll
            for (int m = 0; m < 2; ++m)
                #pragma unroll
                for (int rr = 0; rr < 4; ++rr) {
                    int node = node0 + (mh * 2 + m) * 16 + quad * 4 + rr;
                    if (node < N_NODES)
                        out[node * 160 + 64 + (wh * 16 + l15) * 3 + i] = S1 * o1[i][m][rr];
                }
    }

    // ================ stage H: h = x1 @ Ŵ1 (K=32), contract with x1 -> out0 ================
    {
        short8 aH[12];
        #pragma unroll
        for (int mt = 0; mt < 12; ++mt) {
            U4S8 t; t.u = *(const uint4*)&A_H[(mt * 16 + l15) * AHSTR + quad * 8];
            aH[mt] = t.s;
        }
        const u16* bp = ws + BH_OFF + (u32)wq * 512 + lane * 8;    // + u*2048 per u
        U4S8 bc, bn;
        bc.u = *(const uint4*)(bp);
        for (int u = 0; u < 32; ++u) {
            if (u < 31) bn.u = *(const uint4*)(bp + 2048); else bn = bc;
            bp += 2048;
            #pragma unroll
            for (int i = 0; i < 3; ++i) {
                f32x4 acc[4];
                #pragma unroll
                for (int m = 0; m < 4; ++m) acc[m] = z4;
                #pragma unroll
                for (int m = 0; m < 4; ++m)
                    acc[m] = __builtin_amdgcn_mfma_f32_16x16x32_bf16(aH[i * 4 + m], bc.s, acc[m], 0, 0, 0);
                #pragma unroll
                for (int m = 0; m < 4; ++m) {
                    f32x4 xq = *(const f32x4*)&x1T[(u * 3 + i) * XTSTR + m * 16 + quad * 4];
                    o0[m] += xq * acc[m];
                }
            }
            bc = bn;
        }
    }

    // ---- out0 epilogue ----
    const float C0v = 0.019581512f;                  // sqrt(1/2608)
    #pragma unroll
    for (int mt = 0; mt < 4; ++mt)
        #pragma unroll
        for (int rr = 0; rr < 4; ++rr) {
            int node = node0 + mt * 16 + quad * 4 + rr;
            if (node < N_NODES)
                out[node * 160 + wq * 16 + l15] = C0v * o0[mt][rr];
        }
}

extern "C" void kernel_launch(void* const* d_in, const int* in_sizes, int n_in,
                              void* d_out, int out_size, void* d_ws, size_t ws_size,
                              hipStream_t stream) {
    const float* feats = (const float*)d_in[0];
    const float* msgs  = (const float*)d_in[1];
    const float* W1    = (const float*)d_in[2];
    const float* W2    = (const float*)d_in[3];
    const float* W3    = (const float*)d_in[4];
    const float* W4    = (const float*)d_in[5];
    const float* W5    = (const float*)d_in[6];
    float* out = (float*)d_out;
    u16* ws = (u16*)d_ws;     // needs 786432 B

    hipLaunchKernelGGL(pack_kernel, dim3(393216 / 256), dim3(256), 0, stream,
                       W1, W2, W3, W4, W5, ws);
    hipLaunchKernelGGL(node_block_kernel, dim3((N_NODES + NB - 1) / NB), dim3(256), 0, stream,
                       feats, msgs, ws, out);
}

// Round 5
// 205.360 us; speedup vs baseline: 6.4816x; 6.4816x over previous
//
#include <hip/hip_runtime.h>

typedef unsigned short u16;
typedef unsigned int u32;

#define N_NODES 50000
#define NB      64

// ws regions (u16 element offsets). Total 393216 u16 = 786432 bytes.
#define BG_OFF  0         // g-part B: N=4096 cols, K=64  -> 256 ntiles * 1024
#define BT_OFF  262144    // t-part B: N=1024 cols, K=64  ->  64 ntiles * 1024
#define BH_OFF  327680    // h-part B: N=2048 cols, K=32  -> 128 ntiles * 512

// LDS strides
#define ASTR   72   // A_S row stride (u16): 144B (odd 16B-multiple -> conflict-free b128)
#define AHSTR  40   // A_H row stride (u16): 80B
#define XTSTR  68   // x0T/x1T row stride (f32): 272B, 16B-aligned rows

typedef __attribute__((ext_vector_type(8))) short short8;
typedef __attribute__((ext_vector_type(4))) float f32x4;
union U4S8 { uint4 u; short8 s; };

__device__ __forceinline__ u16 f2bf(float f) {   // RNE f32 -> bf16
    u32 u = __float_as_uint(f);
    return (u16)((u + 0x7fffu + ((u >> 16) & 1u)) >> 16);
}

// ---------------- pack: weights -> bf16, MFMA-B-fragment-ordered ----------------
// B-frag for 16x16x32: lane = quad*16 + l15 holds B[col = ntile*16 + l15][k = ks*32 + quad*8 + jj].
// Storage slot within ntile: ks*512 + lane*8 + jj.
__global__ __launch_bounds__(256)
void pack_kernel(const float* __restrict__ W1, const float* __restrict__ W2,
                 const float* __restrict__ W3, const float* __restrict__ W4,
                 const float* __restrict__ W5, u16* __restrict__ ws) {
    const float INV_SQRT3 = 0.57735026918962576f;
    int T = blockIdx.x * 256 + threadIdx.x;
    float val;
    if (T < BT_OFF) {                       // g-part: Ŵ0[v, u, w], j = u*64+w
        int slot = T;
        int ntile = slot >> 10, rem = slot & 1023;
        int ks = rem >> 9, rem2 = rem & 511;
        int lane = rem2 >> 3, jj = rem2 & 7;
        int v = ks * 32 + (lane >> 4) * 8 + jj;
        int j = ntile * 16 + (lane & 15);
        int u = j >> 6, w = j & 63;
        if (v == u) val = W2[v * 64 + w];
        else {
            int a = min(u, v), b = max(u, v);
            int p = a * (127 - a) / 2 + (b - a - 1);   // triu64 k=1 row-major
            val = 0.5f * W1[p * 64 + w];
        }
    } else if (T < BH_OFF) {                // t-part: W3[u, v, w], j = u*32+w
        int slot = T - BT_OFF;
        int ntile = slot >> 10, rem = slot & 1023;
        int ks = rem >> 9, rem2 = rem & 511;
        int lane = rem2 >> 3, jj = rem2 & 7;
        int v = ks * 32 + (lane >> 4) * 8 + jj;
        int j = ntile * 16 + (lane & 15);
        int u = j >> 5, w = j & 31;
        val = W3[(u * 64 + v) * 32 + w];
    } else {                                // h-part: Ŵ1[v, u, w], j = u*64+w, K=32
        int slot = T - BH_OFF;
        int ntile = slot >> 9, rem = slot & 511;
        int lane = rem >> 3, jj = rem & 7;
        int v = (lane >> 4) * 8 + jj;
        int j = ntile * 16 + (lane & 15);
        int u = j >> 6, w = j & 63;
        if (v == u) val = W5[v * 64 + w] * INV_SQRT3;
        else {
            int a = min(u, v), b = max(u, v);
            int p = a * (63 - a) / 2 + (b - a - 1);    // triu32 k=1
            val = W4[p * 64 + w] * (0.5f * INV_SQRT3);
        }
    }
    ws[T] = f2bf(val);
}

// ---------------- main fused kernel: one barrier, liveness-partitioned stages ----------------
__global__ __launch_bounds__(256)
void node_block_kernel(const float* __restrict__ feats, const float* __restrict__ msgs,
                       const u16* __restrict__ ws, float* __restrict__ out) {
    __shared__ u16  A_S[64 * ASTR];      //  9216 B  bf16 x0 tile   (rows n, cols v<64)
    __shared__ u16  A_H[192 * AHSTR];    // 15360 B  bf16 x1 tile   (rows i*64+n, cols u<32)
    __shared__ float x0T[64 * XTSTR];    // 17408 B  f32  x0^T      ([v][n])
    __shared__ float x1T[96 * XTSTR];    // 26112 B  f32  x1^T      ([u*3+i][n])
    // total 68096 B -> 2 blocks/CU (LDS-capped)

    const int tid = threadIdx.x;
    const int node0 = blockIdx.x * NB;

    // ---- staging: x = feats + msgs, scattered into all 4 LDS forms ----
    for (int k = 0; k < 5; ++k) {
        int chunk = tid + k * 256;
        int idx = chunk * 8;                 // 160 % 8 == 0: never straddles nodes
        int n = (u32)idx / 160u;
        int d = idx - n * 160;
        int g = node0 * 160 + idx;
        float v[8];
        if (g + 8 <= N_NODES * 160) {
            float4 fa0 = *(const float4*)(feats + g);
            float4 fa1 = *(const float4*)(feats + g + 4);
            float4 fb0 = *(const float4*)(msgs + g);
            float4 fb1 = *(const float4*)(msgs + g + 4);
            v[0]=fa0.x+fb0.x; v[1]=fa0.y+fb0.y; v[2]=fa0.z+fb0.z; v[3]=fa0.w+fb0.w;
            v[4]=fa1.x+fb1.x; v[5]=fa1.y+fb1.y; v[6]=fa1.z+fb1.z; v[7]=fa1.w+fb1.w;
        } else {
            #pragma unroll
            for (int j = 0; j < 8; ++j) v[j] = 0.f;
        }
        if (d < 64) {                        // x0 chunk (d..d+7 all < 64)
            uint4 pk;
            pk.x = ((u32)f2bf(v[1]) << 16) | f2bf(v[0]);
            pk.y = ((u32)f2bf(v[3]) << 16) | f2bf(v[2]);
            pk.z = ((u32)f2bf(v[5]) << 16) | f2bf(v[4]);
            pk.w = ((u32)f2bf(v[7]) << 16) | f2bf(v[6]);
            *(uint4*)&A_S[n * ASTR + d] = pk;
            #pragma unroll
            for (int j = 0; j < 8; ++j) x0T[(d + j) * XTSTR + n] = v[j];
        } else {                             // x1 chunk (d..d+7 all >= 64)
            #pragma unroll
            for (int j = 0; j < 8; ++j) {
                int dd = d + j - 64;
                int u = (u32)dd / 3u, i = dd - u * 3;
                A_H[(i * 64 + n) * AHSTR + u] = f2bf(v[j]);
                x1T[(u * 3 + i) * XTSTR + n] = v[j];
            }
        }
    }
    __syncthreads();     // the ONLY barrier

    const int wave = tid >> 6, lane = tid & 63, quad = lane >> 4, l15 = lane & 15;
    const int wq = wave;                 // wave owns out0 cols [wq*16, wq*16+16)
    const f32x4 z4 = {0.f, 0.f, 0.f, 0.f};

    f32x4 o0[4];                         // out0 accumulators (live through S and H only)
    #pragma unroll
    for (int mt = 0; mt < 4; ++mt) o0[mt] = z4;

    // ================ stage S: g = x0 @ Ŵ0 (K=64, N=4096), contract with x0 ================
    {
        short8 aS[4][2];
        #pragma unroll
        for (int mt = 0; mt < 4; ++mt)
            #pragma unroll
            for (int ks = 0; ks < 2; ++ks) {
                U4S8 t; t.u = *(const uint4*)&A_S[(mt * 16 + l15) * ASTR + ks * 32 + quad * 8];
                aS[mt][ks] = t.s;
            }
        const u16* bp = ws + BG_OFF + (u32)wq * 1024 + lane * 8;   // + u*4096 per u
        U4S8 b0c, b1c, b0n, b1n;
        b0c.u = *(const uint4*)(bp);
        b1c.u = *(const uint4*)(bp + 512);
        #pragma unroll 1
        for (int u = 0; u < 64; ++u) {
            if (u < 63) {
                b0n.u = *(const uint4*)(bp + 4096);
                b1n.u = *(const uint4*)(bp + 4096 + 512);
            } else { b0n = b0c; b1n = b1c; }
            bp += 4096;
            f32x4 acc[4];
            #pragma unroll
            for (int mt = 0; mt < 4; ++mt) acc[mt] = z4;
            #pragma unroll
            for (int mt = 0; mt < 4; ++mt)
                acc[mt] = __builtin_amdgcn_mfma_f32_16x16x32_bf16(aS[mt][0], b0c.s, acc[mt], 0, 0, 0);
            #pragma unroll
            for (int mt = 0; mt < 4; ++mt)
                acc[mt] = __builtin_amdgcn_mfma_f32_16x16x32_bf16(aS[mt][1], b1c.s, acc[mt], 0, 0, 0);
            #pragma unroll
            for (int mt = 0; mt < 4; ++mt) {
                f32x4 xq = *(const f32x4*)&x0T[u * XTSTR + mt * 16 + quad * 4];
                o0[mt] += xq * acc[mt];
            }
            b0c = b0n; b1c = b1n;
        }
    }

    // ================ stage H: h = x1 @ Ŵ1 (K=32, N=2048), contract with x1 -> out0 ================
    // i outermost: only 4 A-fragments live; B re-read 3x (L2-resident)
    #pragma unroll 1
    for (int i = 0; i < 3; ++i) {
        short8 aH[4];
        #pragma unroll
        for (int m = 0; m < 4; ++m) {
            U4S8 t; t.u = *(const uint4*)&A_H[((i * 4 + m) * 16 + l15) * AHSTR + quad * 8];
            aH[m] = t.s;
        }
        const u16* bp = ws + BH_OFF + (u32)wq * 512 + lane * 8;    // + u*2048 per u
        U4S8 bc, bn;
        bc.u = *(const uint4*)(bp);
        #pragma unroll 1
        for (int u = 0; u < 32; ++u) {
            if (u < 31) bn.u = *(const uint4*)(bp + 2048); else bn = bc;
            bp += 2048;
            f32x4 acc[4];
            #pragma unroll
            for (int m = 0; m < 4; ++m) acc[m] = z4;
            #pragma unroll
            for (int m = 0; m < 4; ++m)
                acc[m] = __builtin_amdgcn_mfma_f32_16x16x32_bf16(aH[m], bc.s, acc[m], 0, 0, 0);
            #pragma unroll
            for (int m = 0; m < 4; ++m) {
                f32x4 xq = *(const f32x4*)&x1T[(u * 3 + i) * XTSTR + m * 16 + quad * 4];
                o0[m] += xq * acc[m];
            }
            bc = bn;
        }
    }

    // ---- out0 epilogue (o0 dies here, before stage T) ----
    {
        const float C0v = 0.019581512f;              // sqrt(1/2608)
        #pragma unroll
        for (int mt = 0; mt < 4; ++mt)
            #pragma unroll
            for (int rr = 0; rr < 4; ++rr) {
                int node = node0 + mt * 16 + quad * 4 + rr;
                if (node < N_NODES)
                    out[node * 160 + wq * 16 + l15] = C0v * o0[mt][rr];
            }
    }

    // ================ stage T: t = x0 @ W3' (K=64, N=1024), contract with x1 -> out1 ================
    {
        const int mh = wave >> 1, wh = wave & 1;     // wave owns rows [mh*32..+32), w-cols [wh*16..+16)
        short8 aT[2][2];
        #pragma unroll
        for (int m = 0; m < 2; ++m)
            #pragma unroll
            for (int ks = 0; ks < 2; ++ks) {
                U4S8 t; t.u = *(const uint4*)&A_S[((mh * 2 + m) * 16 + l15) * ASTR + ks * 32 + quad * 8];
                aT[m][ks] = t.s;
            }
        f32x4 o1[3][2];
        #pragma unroll
        for (int i = 0; i < 3; ++i)
            #pragma unroll
            for (int m = 0; m < 2; ++m) o1[i][m] = z4;

        const u16* bp = ws + BT_OFF + (u32)wh * 1024 + lane * 8;   // + u*2048 per u
        U4S8 b0c, b1c, b0n, b1n;
        b0c.u = *(const uint4*)(bp);
        b1c.u = *(const uint4*)(bp + 512);
        #pragma unroll 1
        for (int u = 0; u < 32; ++u) {
            if (u < 31) {
                b0n.u = *(const uint4*)(bp + 2048);
                b1n.u = *(const uint4*)(bp + 2048 + 512);
            } else { b0n = b0c; b1n = b1c; }
            bp += 2048;
            f32x4 acc[2];
            #pragma unroll
            for (int m = 0; m < 2; ++m) acc[m] = z4;
            #pragma unroll
            for (int m = 0; m < 2; ++m)
                acc[m] = __builtin_amdgcn_mfma_f32_16x16x32_bf16(aT[m][0], b0c.s, acc[m], 0, 0, 0);
            #pragma unroll
            for (int m = 0; m < 2; ++m)
                acc[m] = __builtin_amdgcn_mfma_f32_16x16x32_bf16(aT[m][1], b1c.s, acc[m], 0, 0, 0);
            #pragma unroll
            for (int i = 0; i < 3; ++i)
                #pragma unroll
                for (int m = 0; m < 2; ++m) {
                    f32x4 xq = *(const f32x4*)&x1T[(u * 3 + i) * XTSTR + (mh * 2 + m) * 16 + quad * 4];
                    o1[i][m] += xq * acc[m];
                }
            b0c = b0n; b1c = b1n;
        }
        const float S1 = 0.022097087f;               // C1/sqrt(3) = sqrt(1/2048)
        #pragma unroll
        for (int i = 0; i < 3; ++i)
            #pragma unroll
            for (int m = 0; m < 2; ++m)
                #pragma unroll
                for (int rr = 0; rr < 4; ++rr) {
                    int node = node0 + (mh * 2 + m) * 16 + quad * 4 + rr;
                    if (node < N_NODES)
                        out[node * 160 + 64 + (wh * 16 + l15) * 3 + i] = S1 * o1[i][m][rr];
                }
    }
}

extern "C" void kernel_launch(void* const* d_in, const int* in_sizes, int n_in,
                              void* d_out, int out_size, void* d_ws, size_t ws_size,
                              hipStream_t stream) {
    const float* feats = (const float*)d_in[0];
    const float* msgs  = (const float*)d_in[1];
    const float* W1    = (const float*)d_in[2];
    const float* W2    = (const float*)d_in[3];
    const float* W3    = (const float*)d_in[4];
    const float* W4    = (const float*)d_in[5];
    const float* W5    = (const float*)d_in[6];
    float* out = (float*)d_out;
    u16* ws = (u16*)d_ws;     // needs 786432 B

    hipLaunchKernelGGL(pack_kernel, dim3(393216 / 256), dim3(256), 0, stream,
                       W1, W2, W3, W4, W5, ws);
    hipLaunchKernelGGL(node_block_kernel, dim3((N_NODES + NB - 1) / NB), dim3(256), 0, stream,
                       feats, msgs, ws, out);
}

// Round 6
// 204.294 us; speedup vs baseline: 6.5154x; 1.0052x over previous
//
#include <hip/hip_runtime.h>
#include <math.h>

typedef unsigned short u16;
typedef unsigned int u32;

#define N_NODES 50000
#define NB      64

// ws regions (u16 element offsets). Total 393216 u16 = 786432 bytes.
#define BG_OFF  0         // g-part B: N=4096 cols (j=u*64+w), K=64
#define BT_OFF  262144    // t-part B: N=1024 cols (j=u*32+w), K=64
#define BH_OFF  327680    // h-part B: N=2048 cols (j=u*64+w), K=32

// LDS strides
#define ASTR   72   // A_S row stride (u16): 144B
#define AHSTR  40   // A_H row stride (u16): 80B
#define XTSTR  68   // x0T/x1T row stride (u16 bf16): 136B, 8B-aligned rows

typedef __attribute__((ext_vector_type(8))) short short8;
typedef __attribute__((ext_vector_type(4))) float f32x4;
union U4S8 { uint4 u; short8 s; };

__device__ __forceinline__ u16 f2bf(float f) {   // RNE f32 -> bf16
    u32 u = __float_as_uint(f);
    return (u16)((u + 0x7fffu + ((u >> 16) & 1u)) >> 16);
}
__device__ __forceinline__ f32x4 bf4(uint2 q) {  // 4 packed bf16 -> f32x4
    f32x4 r;
    r[0] = __uint_as_float(q.x << 16);
    r[1] = __uint_as_float(q.x & 0xffff0000u);
    r[2] = __uint_as_float(q.y << 16);
    r[3] = __uint_as_float(q.y & 0xffff0000u);
    return r;
}

// fragment-slot helpers (16x16x32 B-frag: lane=quad*16+l15 holds B[col][k=quad*8+jj])
__device__ __forceinline__ int gslot(int u, int v, int w) {     // K=64 regions (BG/BT share form)
    int j = u * 64 + w;
    return (j >> 4) * 1024 + (v >> 5) * 512 + (((v >> 3) & 3) * 16 + (j & 15)) * 8 + (v & 7);
}
__device__ __forceinline__ int tslot(int u, int v, int w) {     // t-part: col j = u*32+w
    int j = u * 32 + w;
    return (j >> 4) * 1024 + (v >> 5) * 512 + (((v >> 3) & 3) * 16 + (j & 15)) * 8 + (v & 7);
}
__device__ __forceinline__ int hslot(int u, int v, int w) {     // K=32: no ks term
    int j = u * 64 + w;
    return (j >> 4) * 512 + (((v >> 3) & 3) * 16 + (j & 15)) * 8 + (v & 7);
}

// region sizes (threads)
#define PA (2016 * 64)            // W1 -> g off-diag (dual write)
#define PB (64 * 64)              // W2 -> g diag
#define PC (2048 * 32)            // W3 -> t
#define PD (496 * 64)             // W4 -> h off-diag (dual write)
#define PE (32 * 64)              // W5 -> h diag
#define PTOT (PA + PB + PC + PD + PE)   // 232448

// ---------------- pack: coalesced source reads, fragment-layout scatter writes ----------------
__global__ __launch_bounds__(256)
void pack_kernel(const float* __restrict__ W1, const float* __restrict__ W2,
                 const float* __restrict__ W3, const float* __restrict__ W4,
                 const float* __restrict__ W5, u16* __restrict__ ws) {
    const float INV_SQRT3 = 0.57735026918962576f;
    int T = blockIdx.x * 256 + threadIdx.x;
    if (T < PA) {                                    // W1[p][w], p = triu64 pair
        int p = T >> 6, w = T & 63;
        u16 bv = f2bf(0.5f * W1[T]);
        int a = (int)((127.0f - sqrtf(16129.0f - 8.0f * (float)p)) * 0.5f);
        a = max(0, min(a, 62));
        while (a > 0 && p < a * (127 - a) / 2) --a;
        while (p >= (a + 1) * (126 - a) / 2) ++a;
        int b = a + 1 + (p - a * (127 - a) / 2);
        ws[BG_OFF + gslot(b, a, w)] = bv;            // (v=a, u=b)
        ws[BG_OFF + gslot(a, b, w)] = bv;            // (v=b, u=a)
    } else if (T < PA + PB) {                        // W2[v][w] -> diag
        int t = T - PA;
        int v = t >> 6, w = t & 63;
        ws[BG_OFF + gslot(v, v, w)] = f2bf(W2[t]);
    } else if (T < PA + PB + PC) {                   // W3[(u*64+v)][w]
        int t = T - PA - PB;
        int k = t >> 5, w = t & 31;
        int u = k >> 6, v = k & 63;
        ws[BT_OFF + tslot(u, v, w)] = f2bf(W3[t]);
    } else if (T < PA + PB + PC + PD) {              // W4[p][w], p = triu32 pair
        int t = T - PA - PB - PC;
        int p = t >> 6, w = t & 63;
        u16 bv = f2bf(0.5f * INV_SQRT3 * W4[t]);
        int a = (int)((63.0f - sqrtf(3969.0f - 8.0f * (float)p)) * 0.5f);
        a = max(0, min(a, 30));
        while (a > 0 && p < a * (63 - a) / 2) --a;
        while (p >= (a + 1) * (62 - a) / 2) ++a;
        int b = a + 1 + (p - a * (63 - a) / 2);
        ws[BH_OFF + hslot(b, a, w)] = bv;
        ws[BH_OFF + hslot(a, b, w)] = bv;
    } else if (T < PTOT) {                           // W5[v][w] -> diag
        int t = T - PA - PB - PC - PD;
        int v = t >> 6, w = t & 63;
        ws[BH_OFF + hslot(v, v, w)] = f2bf(INV_SQRT3 * W5[t]);
    }
}

// ---------------- main fused kernel ----------------
__global__ __launch_bounds__(256, 3)
void node_block_kernel(const float* __restrict__ feats, const float* __restrict__ msgs,
                       const u16* __restrict__ ws, float* __restrict__ out) {
    __shared__ u16 A_S[64 * ASTR];       //  9216 B  bf16 x0 tile   (rows n, cols v<64)
    __shared__ u16 A_H[192 * AHSTR];     // 15360 B  bf16 x1 tile   (rows i*64+n, cols u<32)
    __shared__ u16 x0T[64 * XTSTR];      //  8704 B  bf16 x0^T      ([v][n])
    __shared__ u16 x1T[96 * XTSTR];      // 13056 B  bf16 x1^T      ([u*3+i][n])
    // total 46336 B -> 3 blocks/CU (12 waves/CU)

    const int tid = threadIdx.x;
    const int node0 = blockIdx.x * NB;

    // ---- staging: x = feats + msgs, scattered into all 4 LDS forms ----
    for (int k = 0; k < 5; ++k) {
        int chunk = tid + k * 256;
        int idx = chunk * 8;                 // 160 % 8 == 0: never straddles nodes
        int n = (u32)idx / 160u;
        int d = idx - n * 160;
        int g = node0 * 160 + idx;
        float v[8];
        if (g + 8 <= N_NODES * 160) {
            float4 fa0 = *(const float4*)(feats + g);
            float4 fa1 = *(const float4*)(feats + g + 4);
            float4 fb0 = *(const float4*)(msgs + g);
            float4 fb1 = *(const float4*)(msgs + g + 4);
            v[0]=fa0.x+fb0.x; v[1]=fa0.y+fb0.y; v[2]=fa0.z+fb0.z; v[3]=fa0.w+fb0.w;
            v[4]=fa1.x+fb1.x; v[5]=fa1.y+fb1.y; v[6]=fa1.z+fb1.z; v[7]=fa1.w+fb1.w;
        } else {
            #pragma unroll
            for (int j = 0; j < 8; ++j) v[j] = 0.f;
        }
        u16 bv[8];
        #pragma unroll
        for (int j = 0; j < 8; ++j) bv[j] = f2bf(v[j]);
        if (d < 64) {                        // x0 chunk
            uint4 pk;
            pk.x = ((u32)bv[1] << 16) | bv[0];
            pk.y = ((u32)bv[3] << 16) | bv[2];
            pk.z = ((u32)bv[5] << 16) | bv[4];
            pk.w = ((u32)bv[7] << 16) | bv[6];
            *(uint4*)&A_S[n * ASTR + d] = pk;
            #pragma unroll
            for (int j = 0; j < 8; ++j) x0T[(d + j) * XTSTR + n] = bv[j];
        } else {                             // x1 chunk
            #pragma unroll
            for (int j = 0; j < 8; ++j) {
                int dd = d + j - 64;
                int u = (u32)dd / 3u, i = dd - u * 3;
                A_H[(i * 64 + n) * AHSTR + u] = bv[j];
                x1T[(u * 3 + i) * XTSTR + n] = bv[j];
            }
        }
    }
    __syncthreads();     // the ONLY barrier

    const int wave = tid >> 6, lane = tid & 63, quad = lane >> 4, l15 = lane & 15;
    const int wq = wave;                 // wave owns out0 cols [wq*16, wq*16+16)
    const f32x4 z4 = {0.f, 0.f, 0.f, 0.f};

    f32x4 o0[4];                         // out0 accumulators (live through S and H only)
    #pragma unroll
    for (int mt = 0; mt < 4; ++mt) o0[mt] = z4;

    // ================ stage S: g = x0 @ Ŵ0 (K=64, N=4096), contract with x0 ================
    {
        short8 aS[4][2];
        #pragma unroll
        for (int mt = 0; mt < 4; ++mt)
            #pragma unroll
            for (int ks = 0; ks < 2; ++ks) {
                U4S8 t; t.u = *(const uint4*)&A_S[(mt * 16 + l15) * ASTR + ks * 32 + quad * 8];
                aS[mt][ks] = t.s;
            }
        const u16* bp = ws + BG_OFF + (u32)wq * 1024 + lane * 8;   // + u*4096 per u
        U4S8 b0[2], b1[2];
        b0[0].u = *(const uint4*)(bp);
        b1[0].u = *(const uint4*)(bp + 512);
        b0[1].u = *(const uint4*)(bp + 4096);
        b1[1].u = *(const uint4*)(bp + 4096 + 512);
        #pragma unroll 2
        for (int u = 0; u < 64; ++u) {
            const int c = u & 1;
            short8 B0 = b0[c].s, B1 = b1[c].s;
            if (u < 62) {                                         // distance-2 prefetch
                b0[c].u = *(const uint4*)(bp + (u + 2) * 4096);
                b1[c].u = *(const uint4*)(bp + (u + 2) * 4096 + 512);
            }
            f32x4 acc[4];
            #pragma unroll
            for (int mt = 0; mt < 4; ++mt) acc[mt] = z4;
            #pragma unroll
            for (int mt = 0; mt < 4; ++mt)
                acc[mt] = __builtin_amdgcn_mfma_f32_16x16x32_bf16(aS[mt][0], B0, acc[mt], 0, 0, 0);
            #pragma unroll
            for (int mt = 0; mt < 4; ++mt)
                acc[mt] = __builtin_amdgcn_mfma_f32_16x16x32_bf16(aS[mt][1], B1, acc[mt], 0, 0, 0);
            #pragma unroll
            for (int mt = 0; mt < 4; ++mt) {
                f32x4 xq = bf4(*(const uint2*)&x0T[u * XTSTR + mt * 16 + quad * 4]);
                o0[mt] += xq * acc[mt];
            }
        }
    }

    // ================ stage H: h = x1 @ Ŵ1 (K=32, N=2048), contract with x1 -> out0 ================
    #pragma unroll 1
    for (int i = 0; i < 3; ++i) {
        short8 aH[4];
        #pragma unroll
        for (int m = 0; m < 4; ++m) {
            U4S8 t; t.u = *(const uint4*)&A_H[((i * 4 + m) * 16 + l15) * AHSTR + quad * 8];
            aH[m] = t.s;
        }
        const u16* bp = ws + BH_OFF + (u32)wq * 512 + lane * 8;    // + u*2048 per u
        U4S8 bc, bn;
        bc.u = *(const uint4*)(bp);
        #pragma unroll 1
        for (int u = 0; u < 32; ++u) {
            if (u < 31) bn.u = *(const uint4*)(bp + 2048); else bn = bc;
            bp += 2048;
            f32x4 acc[4];
            #pragma unroll
            for (int m = 0; m < 4; ++m) acc[m] = z4;
            #pragma unroll
            for (int m = 0; m < 4; ++m)
                acc[m] = __builtin_amdgcn_mfma_f32_16x16x32_bf16(aH[m], bc.s, acc[m], 0, 0, 0);
            #pragma unroll
            for (int m = 0; m < 4; ++m) {
                f32x4 xq = bf4(*(const uint2*)&x1T[(u * 3 + i) * XTSTR + m * 16 + quad * 4]);
                o0[m] += xq * acc[m];
            }
            bc = bn;
        }
    }

    // ---- out0 epilogue (o0 dies here, before stage T) ----
    {
        const float C0v = 0.019581512f;              // sqrt(1/2608)
        #pragma unroll
        for (int mt = 0; mt < 4; ++mt)
            #pragma unroll
            for (int rr = 0; rr < 4; ++rr) {
                int node = node0 + mt * 16 + quad * 4 + rr;
                if (node < N_NODES)
                    out[node * 160 + wq * 16 + l15] = C0v * o0[mt][rr];
            }
    }

    // ================ stage T: t = x0 @ W3' (K=64, N=1024), contract with x1 -> out1 ================
    {
        const int mh = wave >> 1, wh = wave & 1;     // wave owns rows [mh*32..+32), w-cols [wh*16..+16)
        short8 aT[2][2];
        #pragma unroll
        for (int m = 0; m < 2; ++m)
            #pragma unroll
            for (int ks = 0; ks < 2; ++ks) {
                U4S8 t; t.u = *(const uint4*)&A_S[((mh * 2 + m) * 16 + l15) * ASTR + ks * 32 + quad * 8];
                aT[m][ks] = t.s;
            }
        f32x4 o1[3][2];
        #pragma unroll
        for (int i = 0; i < 3; ++i)
            #pragma unroll
            for (int m = 0; m < 2; ++m) o1[i][m] = z4;

        const u16* bp = ws + BT_OFF + (u32)wh * 1024 + lane * 8;   // + u*2048 per u
        U4S8 b0[2], b1[2];
        b0[0].u = *(const uint4*)(bp);
        b1[0].u = *(const uint4*)(bp + 512);
        b0[1].u = *(const uint4*)(bp + 2048);
        b1[1].u = *(const uint4*)(bp + 2048 + 512);
        #pragma unroll 2
        for (int u = 0; u < 32; ++u) {
            const int c = u & 1;
            short8 B0 = b0[c].s, B1 = b1[c].s;
            if (u < 30) {                                          // distance-2 prefetch
                b0[c].u = *(const uint4*)(bp + (u + 2) * 2048);
                b1[c].u = *(const uint4*)(bp + (u + 2) * 2048 + 512);
            }
            f32x4 acc[2];
            #pragma unroll
            for (int m = 0; m < 2; ++m) acc[m] = z4;
            #pragma unroll
            for (int m = 0; m < 2; ++m)
                acc[m] = __builtin_amdgcn_mfma_f32_16x16x32_bf16(aT[m][0], B0, acc[m], 0, 0, 0);
            #pragma unroll
            for (int m = 0; m < 2; ++m)
                acc[m] = __builtin_amdgcn_mfma_f32_16x16x32_bf16(aT[m][1], B1, acc[m], 0, 0, 0);
            #pragma unroll
            for (int i = 0; i < 3; ++i)
                #pragma unroll
                for (int m = 0; m < 2; ++m) {
                    f32x4 xq = bf4(*(const uint2*)&x1T[(u * 3 + i) * XTSTR + (mh * 2 + m) * 16 + quad * 4]);
                    o1[i][m] += xq * acc[m];
                }
        }
        const float S1 = 0.022097087f;               // C1/sqrt(3) = sqrt(1/2048)
        #pragma unroll
        for (int i = 0; i < 3; ++i)
            #pragma unroll
            for (int m = 0; m < 2; ++m)
                #pragma unroll
                for (int rr = 0; rr < 4; ++rr) {
                    int node = node0 + (mh * 2 + m) * 16 + quad * 4 + rr;
                    if (node < N_NODES)
                        out[node * 160 + 64 + (wh * 16 + l15) * 3 + i] = S1 * o1[i][m][rr];
                }
    }
}

extern "C" void kernel_launch(void* const* d_in, const int* in_sizes, int n_in,
                              void* d_out, int out_size, void* d_ws, size_t ws_size,
                              hipStream_t stream) {
    const float* feats = (const float*)d_in[0];
    const float* msgs  = (const float*)d_in[1];
    const float* W1    = (const float*)d_in[2];
    const float* W2    = (const float*)d_in[3];
    const float* W3    = (const float*)d_in[4];
    const float* W4    = (const float*)d_in[5];
    const float* W5    = (const float*)d_in[6];
    float* out = (float*)d_out;
    u16* ws = (u16*)d_ws;     // needs 786432 B

    hipLaunchKernelGGL(pack_kernel, dim3((PTOT + 255) / 256), dim3(256), 0, stream,
                       W1, W2, W3, W4, W5, ws);
    hipLaunchKernelGGL(node_block_kernel, dim3((N_NODES + NB - 1) / NB), dim3(256), 0, stream,
                       feats, msgs, ws, out);
}

// Round 7
// 197.834 us; speedup vs baseline: 6.7281x; 1.0326x over previous
//
#include <hip/hip_runtime.h>

typedef unsigned short u16;
typedef unsigned int u32;

#define N_NODES 50000
#define NB      64

// ws regions (u16 element offsets). Total 393216 u16 = 786432 bytes.
#define BG_OFF  0         // g-part B: N=4096 cols (j=u*64+w), K=64
#define BT_OFF  262144    // t-part B: N=1024 cols (j=u*32+w), K=64
#define BH_OFF  327680    // h-part B: N=2048 cols (j=u*64+w), K=32

// LDS strides
#define ASTR   72   // A_S row stride (u16): 144B
#define AHSTR  40   // A_H row stride (u16): 80B
#define XTSTR  68   // x0T/x1T row stride (u16 bf16): 136B

typedef __attribute__((ext_vector_type(8))) short short8;
typedef __attribute__((ext_vector_type(4))) float f32x4;
union U4S8 { uint4 u; short8 s; };

__device__ __forceinline__ u16 f2bf(float f) {   // RNE f32 -> bf16
    u32 u = __float_as_uint(f);
    return (u16)((u + 0x7fffu + ((u >> 16) & 1u)) >> 16);
}
__device__ __forceinline__ f32x4 bf4(uint2 q) {  // 4 packed bf16 -> f32x4
    f32x4 r;
    r[0] = __uint_as_float(q.x << 16);
    r[1] = __uint_as_float(q.x & 0xffff0000u);
    r[2] = __uint_as_float(q.y << 16);
    r[3] = __uint_as_float(q.y & 0xffff0000u);
    return r;
}

// ---------------- pack: output-indexed, coalesced uint4 writes, gather reads ----------------
// B-frag layout (16x16x32): slot-in-ntile = ks*512 + (((v>>3)&3)*16 + (j&15))*8 + (v&7)
// BG/BT: ntile = j>>4 with 64 k's (ks=v>>5); BH: K=32, no ks term.
__global__ __launch_bounds__(256)
void pack_kernel(const float* __restrict__ W1, const float* __restrict__ W2,
                 const float* __restrict__ W3, const float* __restrict__ W4,
                 const float* __restrict__ W5, u16* __restrict__ ws) {
    const float INV_SQRT3 = 0.57735026918962576f;
    int T = blockIdx.x * 256 + threadIdx.x;       // 49152 threads
    int slot0 = T * 8;                             // 8 consecutive slots (jj = v&7 = 0..7)
    float vals[8];
    if (slot0 < BT_OFF) {                          // ---- BG: Ŵ0[v, u, w] ----
        int ntile = slot0 >> 10, rem = slot0 & 1023;
        int ks = rem >> 9, q = (rem & 511) >> 3;
        int vbase = ks * 32 + (q >> 4) * 8;
        int j = ntile * 16 + (q & 15);
        int u = j >> 6, w = j & 63;
        #pragma unroll
        for (int jj = 0; jj < 8; ++jj) {
            int v = vbase + jj;
            if (v == u) vals[jj] = W2[u * 64 + w];
            else {
                int a = min(u, v), b = max(u, v);
                int p = a * (127 - a) / 2 + (b - a - 1);   // triu64 k=1 row-major
                vals[jj] = 0.5f * W1[p * 64 + w];
            }
        }
    } else if (slot0 < BH_OFF) {                   // ---- BT: W3[u, v, w], col j=u*32+w ----
        int s = slot0 - BT_OFF;
        int ntile = s >> 10, rem = s & 1023;
        int ks = rem >> 9, q = (rem & 511) >> 3;
        int vbase = ks * 32 + (q >> 4) * 8;
        int j = ntile * 16 + (q & 15);
        int u = j >> 5, w = j & 31;
        #pragma unroll
        for (int jj = 0; jj < 8; ++jj)
            vals[jj] = W3[(u * 64 + (vbase + jj)) * 32 + w];
    } else {                                       // ---- BH: Ŵ1[v, u, w], K=32 ----
        int s = slot0 - BH_OFF;
        int ntile = s >> 9, q = (s & 511) >> 3;
        int vbase = (q >> 4) * 8;
        int j = ntile * 16 + (q & 15);
        int u = j >> 6, w = j & 63;
        #pragma unroll
        for (int jj = 0; jj < 8; ++jj) {
            int v = vbase + jj;
            if (v == u) vals[jj] = W5[u * 64 + w] * INV_SQRT3;
            else {
                int a = min(u, v), b = max(u, v);
                int p = a * (63 - a) / 2 + (b - a - 1);    // triu32 k=1
                vals[jj] = (0.5f * INV_SQRT3) * W4[p * 64 + w];
            }
        }
    }
    uint4 o;
    o.x = ((u32)f2bf(vals[1]) << 16) | f2bf(vals[0]);
    o.y = ((u32)f2bf(vals[3]) << 16) | f2bf(vals[2]);
    o.z = ((u32)f2bf(vals[5]) << 16) | f2bf(vals[4]);
    o.w = ((u32)f2bf(vals[7]) << 16) | f2bf(vals[6]);
    *(uint4*)(ws + slot0) = o;                     // coalesced 16B store
}

// ---------------- main fused kernel: phase-rotated K-loops ----------------
__global__ __launch_bounds__(256, 3)
void node_block_kernel(const float* __restrict__ feats, const float* __restrict__ msgs,
                       const u16* __restrict__ ws, float* __restrict__ out) {
    __shared__ u16 A_S[64 * ASTR];       //  9216 B  bf16 x0 tile   (rows n, cols v<64)
    __shared__ u16 A_H[192 * AHSTR];     // 15360 B  bf16 x1 tile   (rows i*64+n, cols u<32)
    __shared__ u16 x0T[64 * XTSTR];      //  8704 B  bf16 x0^T      ([v][n])
    __shared__ u16 x1T[96 * XTSTR];      // 13056 B  bf16 x1^T      ([u*3+i][n])
    // total 46336 B -> 3 blocks/CU (12 waves/CU)

    const int tid = threadIdx.x;
    const int node0 = blockIdx.x * NB;

    // ---- staging: x = feats + msgs, scattered into all 4 LDS forms ----
    for (int k = 0; k < 5; ++k) {
        int chunk = tid + k * 256;
        int idx = chunk * 8;                 // 160 % 8 == 0: never straddles nodes
        int n = (u32)idx / 160u;
        int d = idx - n * 160;
        int g = node0 * 160 + idx;
        float v[8];
        if (g + 8 <= N_NODES * 160) {
            float4 fa0 = *(const float4*)(feats + g);
            float4 fa1 = *(const float4*)(feats + g + 4);
            float4 fb0 = *(const float4*)(msgs + g);
            float4 fb1 = *(const float4*)(msgs + g + 4);
            v[0]=fa0.x+fb0.x; v[1]=fa0.y+fb0.y; v[2]=fa0.z+fb0.z; v[3]=fa0.w+fb0.w;
            v[4]=fa1.x+fb1.x; v[5]=fa1.y+fb1.y; v[6]=fa1.z+fb1.z; v[7]=fa1.w+fb1.w;
        } else {
            #pragma unroll
            for (int j = 0; j < 8; ++j) v[j] = 0.f;
        }
        u16 bv[8];
        #pragma unroll
        for (int j = 0; j < 8; ++j) bv[j] = f2bf(v[j]);
        if (d < 64) {                        // x0 chunk
            uint4 pk;
            pk.x = ((u32)bv[1] << 16) | bv[0];
            pk.y = ((u32)bv[3] << 16) | bv[2];
            pk.z = ((u32)bv[5] << 16) | bv[4];
            pk.w = ((u32)bv[7] << 16) | bv[6];
            *(uint4*)&A_S[n * ASTR + d] = pk;
            #pragma unroll
            for (int j = 0; j < 8; ++j) x0T[(d + j) * XTSTR + n] = bv[j];
        } else {                             // x1 chunk
            #pragma unroll
            for (int j = 0; j < 8; ++j) {
                int dd = d + j - 64;
                int u = (u32)dd / 3u, i = dd - u * 3;
                A_H[(i * 64 + n) * AHSTR + u] = bv[j];
                x1T[(u * 3 + i) * XTSTR + n] = bv[j];
            }
        }
    }
    __syncthreads();     // the ONLY barrier

    const int wave = tid >> 6, lane = tid & 63, quad = lane >> 4, l15 = lane & 15;
    const int wq = wave;                 // wave owns out0 cols [wq*16, wq*16+16)
    const f32x4 z4 = {0.f, 0.f, 0.f, 0.f};
    const int ph64 = (blockIdx.x * 5) & 63;   // per-block K-loop phase (decorrelate L2 lines)
    const int ph32 = (blockIdx.x * 5) & 31;

    f32x4 o0[4];                         // out0 accumulators (live through S and H only)
    #pragma unroll
    for (int mt = 0; mt < 4; ++mt) o0[mt] = z4;

    // ================ stage S: g = x0 @ Ŵ0 (K=64, N=4096), contract with x0 ================
    {
        short8 aS[4][2];
        #pragma unroll
        for (int mt = 0; mt < 4; ++mt)
            #pragma unroll
            for (int ks = 0; ks < 2; ++ks) {
                U4S8 t; t.u = *(const uint4*)&A_S[(mt * 16 + l15) * ASTR + ks * 32 + quad * 8];
                aS[mt][ks] = t.s;
            }
        const u16* bp = ws + BG_OFF + (u32)wq * 1024 + lane * 8;   // + u*4096 per u
        U4S8 b0[2], b1[2];
        b0[0].u = *(const uint4*)(bp + ph64 * 4096);
        b1[0].u = *(const uint4*)(bp + ph64 * 4096 + 512);
        {
            int p1 = ((ph64 + 1) & 63) * 4096;
            b0[1].u = *(const uint4*)(bp + p1);
            b1[1].u = *(const uint4*)(bp + p1 + 512);
        }
        #pragma unroll 2
        for (int t = 0; t < 64; ++t) {
            const int c = t & 1;
            const int u = (ph64 + t) & 63;
            short8 B0 = b0[c].s, B1 = b1[c].s;
            if (t < 62) {                                         // distance-2 prefetch
                int pp = ((ph64 + t + 2) & 63) * 4096;
                b0[c].u = *(const uint4*)(bp + pp);
                b1[c].u = *(const uint4*)(bp + pp + 512);
            }
            f32x4 acc[4];
            #pragma unroll
            for (int mt = 0; mt < 4; ++mt) acc[mt] = z4;
            #pragma unroll
            for (int mt = 0; mt < 4; ++mt)
                acc[mt] = __builtin_amdgcn_mfma_f32_16x16x32_bf16(aS[mt][0], B0, acc[mt], 0, 0, 0);
            #pragma unroll
            for (int mt = 0; mt < 4; ++mt)
                acc[mt] = __builtin_amdgcn_mfma_f32_16x16x32_bf16(aS[mt][1], B1, acc[mt], 0, 0, 0);
            #pragma unroll
            for (int mt = 0; mt < 4; ++mt) {
                f32x4 xq = bf4(*(const uint2*)&x0T[u * XTSTR + mt * 16 + quad * 4]);
                o0[mt] += xq * acc[mt];
            }
        }
    }

    // ================ stage H: h = x1 @ Ŵ1 (K=32, N=2048), merged i, contract -> out0 ================
    {
        short8 aH[12];
        #pragma unroll
        for (int m = 0; m < 12; ++m) {
            U4S8 t; t.u = *(const uint4*)&A_H[(m * 16 + l15) * AHSTR + quad * 8];
            aH[m] = t.s;
        }
        const u16* bp = ws + BH_OFF + (u32)wq * 512 + lane * 8;    // + u*2048 per u
        U4S8 bb[2];
        bb[0].u = *(const uint4*)(bp + ph32 * 2048);
        bb[1].u = *(const uint4*)(bp + ((ph32 + 1) & 31) * 2048);
        #pragma unroll 2
        for (int t = 0; t < 32; ++t) {
            const int c = t & 1;
            const int u = (ph32 + t) & 31;
            short8 B = bb[c].s;
            if (t < 30) bb[c].u = *(const uint4*)(bp + ((ph32 + t + 2) & 31) * 2048);
            #pragma unroll
            for (int i = 0; i < 3; ++i) {
                f32x4 acc[4];
                #pragma unroll
                for (int m = 0; m < 4; ++m) acc[m] = z4;
                #pragma unroll
                for (int m = 0; m < 4; ++m)
                    acc[m] = __builtin_amdgcn_mfma_f32_16x16x32_bf16(aH[i * 4 + m], B, acc[m], 0, 0, 0);
                #pragma unroll
                for (int m = 0; m < 4; ++m) {
                    f32x4 xq = bf4(*(const uint2*)&x1T[(u * 3 + i) * XTSTR + m * 16 + quad * 4]);
                    o0[m] += xq * acc[m];
                }
            }
        }
    }

    // ---- out0 epilogue (o0 dies here, before stage T) ----
    {
        const float C0v = 0.019581512f;              // sqrt(1/2608)
        #pragma unroll
        for (int mt = 0; mt < 4; ++mt)
            #pragma unroll
            for (int rr = 0; rr < 4; ++rr) {
                int node = node0 + mt * 16 + quad * 4 + rr;
                if (node < N_NODES)
                    out[node * 160 + wq * 16 + l15] = C0v * o0[mt][rr];
            }
    }

    // ================ stage T: t = x0 @ W3' (K=64, N=1024), contract with x1 -> out1 ================
    {
        const int mh = wave >> 1, wh = wave & 1;     // wave owns rows [mh*32..+32), w-cols [wh*16..+16)
        short8 aT[2][2];
        #pragma unroll
        for (int m = 0; m < 2; ++m)
            #pragma unroll
            for (int ks = 0; ks < 2; ++ks) {
                U4S8 t; t.u = *(const uint4*)&A_S[((mh * 2 + m) * 16 + l15) * ASTR + ks * 32 + quad * 8];
                aT[m][ks] = t.s;
            }
        f32x4 o1[3][2];
        #pragma unroll
        for (int i = 0; i < 3; ++i)
            #pragma unroll
            for (int m = 0; m < 2; ++m) o1[i][m] = z4;

        const u16* bp = ws + BT_OFF + (u32)wh * 1024 + lane * 8;   // + u*2048 per u
        U4S8 b0[2], b1[2];
        b0[0].u = *(const uint4*)(bp + ph32 * 2048);
        b1[0].u = *(const uint4*)(bp + ph32 * 2048 + 512);
        {
            int p1 = ((ph32 + 1) & 31) * 2048;
            b0[1].u = *(const uint4*)(bp + p1);
            b1[1].u = *(const uint4*)(bp + p1 + 512);
        }
        #pragma unroll 2
        for (int t = 0; t < 32; ++t) {
            const int c = t & 1;
            const int u = (ph32 + t) & 31;
            short8 B0 = b0[c].s, B1 = b1[c].s;
            if (t < 30) {                                          // distance-2 prefetch
                int pp = ((ph32 + t + 2) & 31) * 2048;
                b0[c].u = *(const uint4*)(bp + pp);
                b1[c].u = *(const uint4*)(bp + pp + 512);
            }
            f32x4 acc[2];
            #pragma unroll
            for (int m = 0; m < 2; ++m) acc[m] = z4;
            #pragma unroll
            for (int m = 0; m < 2; ++m)
                acc[m] = __builtin_amdgcn_mfma_f32_16x16x32_bf16(aT[m][0], B0, acc[m], 0, 0, 0);
            #pragma unroll
            for (int m = 0; m < 2; ++m)
                acc[m] = __builtin_amdgcn_mfma_f32_16x16x32_bf16(aT[m][1], B1, acc[m], 0, 0, 0);
            #pragma unroll
            for (int i = 0; i < 3; ++i)
                #pragma unroll
                for (int m = 0; m < 2; ++m) {
                    f32x4 xq = bf4(*(const uint2*)&x1T[(u * 3 + i) * XTSTR + (mh * 2 + m) * 16 + quad * 4]);
                    o1[i][m] += xq * acc[m];
                }
        }
        const float S1 = 0.022097087f;               // C1/sqrt(3) = sqrt(1/2048)
        #pragma unroll
        for (int i = 0; i < 3; ++i)
            #pragma unroll
            for (int m = 0; m < 2; ++m)
                #pragma unroll
                for (int rr = 0; rr < 4; ++rr) {
                    int node = node0 + (mh * 2 + m) * 16 + quad * 4 + rr;
                    if (node < N_NODES)
                        out[node * 160 + 64 + (wh * 16 + l15) * 3 + i] = S1 * o1[i][m][rr];
                }
    }
}

extern "C" void kernel_launch(void* const* d_in, const int* in_sizes, int n_in,
                              void* d_out, int out_size, void* d_ws, size_t ws_size,
                              hipStream_t stream) {
    const float* feats = (const float*)d_in[0];
    const float* msgs  = (const float*)d_in[1];
    const float* W1    = (const float*)d_in[2];
    const float* W2    = (const float*)d_in[3];
    const float* W3    = (const float*)d_in[4];
    const float* W4    = (const float*)d_in[5];
    const float* W5    = (const float*)d_in[6];
    float* out = (float*)d_out;
    u16* ws = (u16*)d_ws;     // needs 786432 B

    hipLaunchKernelGGL(pack_kernel, dim3(192), dim3(256), 0, stream,
                       W1, W2, W3, W4, W5, ws);
    hipLaunchKernelGGL(node_block_kernel, dim3((N_NODES + NB - 1) / NB), dim3(256), 0, stream,
                       feats, msgs, ws, out);
}